// Round 18
// baseline (119.542 us; speedup 1.0000x reference)
//
#include <hip/hip_runtime.h>

#define B_ 32
#define D_ 64
#define N_ 254
#define L_ 16
#define H_ 128
#define P_ 96
#define PAIRS (B_*D_)    // 2048
#define XPAIR (N_*L_)    // 4064 floats per (b,d) pair
#define OUT0  (B_*P_*D_) // 196608 floats (output 0)

// ws layout (floats):
#define WS_M    128    // [256]  M = W_enc W_enc^T  ([l1*16+l2])
#define WS_VK   384    // [16]   W_enc @ K,  K = 254*b_enc + colsum(pos)
#define WS_BW   400    // [16]   W_enc @ b_enc
#define WS_BK   416    // [1]    b_enc . K
#define WS_G    432    // [254*16] pos @ W_enc^T  ([n*16+l])
#define WS_PK   4496   // [254]  pos @ K
#define WS_KP   4752   // [16*128] partial column sums of pos

typedef float f32x4 __attribute__((ext_vector_type(4)));

__device__ __forceinline__ f32x4 sx4(f32x4 v, int m) {
    f32x4 r;
    r[0] = __shfl_xor(v[0], m); r[1] = __shfl_xor(v[1], m);
    r[2] = __shfl_xor(v[2], m); r[3] = __shfl_xor(v[3], m);
    return r;
}

// ---- stage 1: partial column sums of pos (254 x 128), coalesced ----
__global__ __launch_bounds__(256) void preK(const float* __restrict__ pos,
                                            float* __restrict__ ws) {
    __shared__ float red[256];
    int t = threadIdx.x;
    int h = t & 127, j = t >> 7;          // j in {0,1}
    int n0 = blockIdx.x * 16;             // 16 blocks x 16 rows (last: 14)
    float acc = 0.f;
    #pragma unroll
    for (int r = 0; r < 8; r++) {
        int n = n0 + j + 2 * r;
        if (n < N_) acc += pos[n * H_ + h];
    }
    red[t] = acc;
    __syncthreads();
    if (t < 128) ws[WS_KP + blockIdx.x * 128 + t] = red[t] + red[t + 128];
}

// ---- stage 2: G,pK (blocks 0..253) + M,vK,bW,bK (block 254) ----
__global__ __launch_bounds__(128) void pre2b(const float* __restrict__ W_enc,
                                             const float* __restrict__ b_enc,
                                             const float* __restrict__ pos,
                                             float* __restrict__ ws) {
    __shared__ float Ks[128], bL[128], pLDS[128], red[128], red2[128];
    __shared__ float WL[2048];
    int t = threadIdx.x;                  // 128 threads
    int n = blockIdx.x;                   // 0..254

    // rebuild K locally (L2-hot partials): K[h] = 254*b_enc[h] + sum_g part
    {
        float b = b_enc[t];
        float s = 254.f * b;
        #pragma unroll
        for (int g = 0; g < 16; g++) s += ws[WS_KP + g * 128 + t];
        Ks[t] = s;
        bL[t] = b;
    }

    if (n < N_) {
        pLDS[t] = pos[n * H_ + t];
        __syncthreads();
        // G partials: t -> (l = t>>3, c = t&7), 16-wide h-chunk each
        {
            int l = t >> 3, c = t & 7;
            const float* w = W_enc + l * H_ + c * 16;
            const float* p = pLDS + c * 16;
            float s = 0.f;
            #pragma unroll
            for (int i = 0; i < 16; i++) s += p[i] * w[i];
            red[t] = s;
            red2[t] = pLDS[t] * Ks[t];
        }
        __syncthreads();
        if (t < 16) {                     // G final
            float s = 0.f;
            #pragma unroll
            for (int c = 0; c < 8; c++) s += red[t * 8 + c];
            ws[WS_G + n * 16 + t] = s;
        }
        if (t >= 64) {                    // pK final (wave 1)
            int lane = t - 64;
            float s = red2[lane] + red2[lane + 64];
            for (int off = 32; off; off >>= 1) s += __shfl_down(s, off);
            if (lane == 0) ws[WS_PK + n] = s;
        }
    } else {
        // block 254: stage W_enc (16x128) into LDS, then tiny dots
        for (int i = t; i < 512; i += 128) {
            float4 v = ((const float4*)W_enc)[i];
            float* p = &WL[i * 4];
            p[0] = v.x; p[1] = v.y; p[2] = v.z; p[3] = v.w;
        }
        __syncthreads();
        #pragma unroll
        for (int e0 = 0; e0 < 2; e0++) {  // M: 256 entries / 128 threads
            int e = e0 * 128 + t;
            int l1 = e >> 4, l2 = e & 15;
            float s = 0.f;
            for (int h = 0; h < H_; h++) s += WL[l1 * H_ + h] * WL[l2 * H_ + h];
            ws[WS_M + e] = s;
        }
        if (t < 16) {
            float s1 = 0.f, s2 = 0.f;
            for (int h = 0; h < H_; h++) {
                float w = WL[t * H_ + h];
                s1 += w * Ks[h];
                s2 += w * bL[h];
            }
            ws[WS_VK + t] = s1;
            ws[WS_BW + t] = s2;
        }
        if (t == 16) {
            float s = 0.f;
            for (int h = 0; h < H_; h++) s += bL[h] * Ks[h];
            ws[WS_BK] = s;
        }
    }
}

// ---- main: x in registers; deferred copy-stores (R17, -1.9us); reduction
//      trees replaced by in-wave shfl butterflies -> 6 barriers instead of 8.
//      Wave w's lanes 0..3 publish 4 f32x4 wave-partials; wave0 finalizes. ----
__global__ __launch_bounds__(256) void mainker(const float* __restrict__ x,
                                               const float* __restrict__ W1,
                                               const float* __restrict__ b1,
                                               const float* __restrict__ W2,
                                               const float* __restrict__ b2,
                                               const float* __restrict__ ws,
                                               float* __restrict__ out) {
    __shared__ f32x4 red4[16];           // 4 waves x 4 quads
    __shared__ float scoreS[256];        // padded to 256
    __shared__ float xsS[16], vS[16], pooledS[16], hS[128];
    __shared__ float s0S, denomS;

    int t  = threadIdx.x;
    int bd = blockIdx.x;                 // b*64 + d
    int q  = t & 3, r0 = t >> 2;         // quad, base row
    int wv = t >> 6, lane = t & 63;

    const f32x4* xv = (const f32x4*)(x + (size_t)bd * XPAIR);
    f32x4*       cv = (f32x4*)(out + OUT0) + (size_t)bd * (XPAIR / 4);

    f32x4 v0 = xv[t];
    f32x4 v1 = xv[t + 256];
    f32x4 v2 = xv[t + 512];
    f32x4 v3 = {0.f, 0.f, 0.f, 0.f};
    bool has3 = (t < 248);               // rows 254/255 don't exist
    if (has3) v3 = xv[t + 768];

    // ---- xs: in-wave butterfly over same-q lanes, then 4 wave-partials ----
    {
        f32x4 p4 = v0 + v1 + v2 + v3;
        p4 = p4 + sx4(p4, 4); p4 = p4 + sx4(p4, 8);
        p4 = p4 + sx4(p4, 16); p4 = p4 + sx4(p4, 32);
        if (lane < 4) red4[wv * 4 + lane] = p4;   // lane == q for lanes 0..3
    }
    __syncthreads();

    // ---- wave0: xs final + v = vK + M xs + s0 = bK + xs.bW ----
    if (t < 16) {
        f32x4 xr = red4[t >> 2] + red4[4 + (t >> 2)] + red4[8 + (t >> 2)] + red4[12 + (t >> 2)];
        float xsv = xr[t & 3];
        xsS[t] = xsv;
        float s = ws[WS_VK + t];
        #pragma unroll
        for (int l2 = 0; l2 < 16; l2++) s += __shfl(xsv, l2) * ws[WS_M + l2 * 16 + t];
        vS[t] = s;
        float s0p = xsv * ws[WS_BW + t];
        #pragma unroll
        for (int off = 8; off; off >>= 1) s0p += __shfl_down(s0p, off);
        if (t == 0) s0S = ws[WS_BK] + s0p;
    }
    __syncthreads();

    // ---- score[n] by 4-lane groups from registers; G reads coalesced float4 ----
    {
        float vq0 = vS[4*q], vq1 = vS[4*q+1], vq2 = vS[4*q+2], vq3 = vS[4*q+3];
        float xq0 = xsS[4*q], xq1 = xsS[4*q+1], xq2 = xsS[4*q+2], xq3 = xsS[4*q+3];
        #pragma unroll
        for (int k = 0; k < 4; k++) {
            if (k < 3 || has3) {
                int rk = r0 + 64 * k;
                f32x4 xk = (k == 0) ? v0 : (k == 1) ? v1 : (k == 2) ? v2 : v3;
                f32x4 g  = *(const f32x4*)(ws + WS_G + rk * 16 + 4 * q);
                float s = xk[0]*vq0 + xk[1]*vq1 + xk[2]*vq2 + xk[3]*vq3
                        + xq0*g[0] + xq1*g[1] + xq2*g[2] + xq3*g[3];
                s += __shfl_xor(s, 1);
                s += __shfl_xor(s, 2);
                if (q == 0) scoreS[rk] = s + s0S + ws[WS_PK + rk];
            }
        }
    }
    __syncthreads();

    // ---- denom (wave 0) + pooled butterfly (all waves), one barrier ----
    if (t < 64) {
        float s = 0.f;
        for (int n = t; n < N_; n += 64) s += fabsf(scoreS[n]);
        for (int off = 32; off; off >>= 1) s += __shfl_down(s, off);
        if (t == 0) denomS = s;
    }
    {
        f32x4 p4 = v0 * scoreS[r0] + v1 * scoreS[r0 + 64] + v2 * scoreS[r0 + 128];
        if (has3) p4 += v3 * scoreS[r0 + 192];
        p4 = p4 + sx4(p4, 4); p4 = p4 + sx4(p4, 8);
        p4 = p4 + sx4(p4, 16); p4 = p4 + sx4(p4, 32);
        if (lane < 4) red4[wv * 4 + lane] = p4;
    }
    __syncthreads();
    if (t < 16) {
        float invd = 1.0f / denomS;
        f32x4 pr = red4[t >> 2] + red4[4 + (t >> 2)] + red4[8 + (t >> 2)] + red4[12 + (t >> 2)];
        pooledS[t] = pr[t & 3] * invd;
    }
    __syncthreads();

    // ---- h = leaky_relu(pooled @ W1 + b1, 0.2) ----
    if (t < 128) {
        float s = b1[t];
        #pragma unroll
        for (int l = 0; l < 16; l++) s += pooledS[l] * W1[l * H_ + t];
        hS[t] = s > 0.f ? s : 0.2f * s;
    }
    __syncthreads();

    // ---- deferred copy-stores: after the last barrier, no barrier waits on them ----
    cv[t]       = v0;
    cv[t + 256] = v1;
    cv[t + 512] = v2;
    if (has3) cv[t + 768] = v3;

    // ---- out0[b, p, d] = h @ W2 + b2 : coalesced scalar W2 (lane-consecutive) ----
    if (t < 96) {
        float s = b2[t];
        for (int j = 0; j < 128; j++) s += hS[j] * W2[j * P_ + t];
        int b = bd >> 6, d = bd & 63;
        out[b * (P_ * D_) + t * D_ + d] = s;
    }
}

extern "C" void kernel_launch(void* const* d_in, const int* in_sizes, int n_in,
                              void* d_out, int out_size, void* d_ws, size_t ws_size,
                              hipStream_t stream) {
    const float* x     = (const float*)d_in[0];
    const float* W_enc = (const float*)d_in[1];
    const float* b_enc = (const float*)d_in[2];
    const float* W1    = (const float*)d_in[3];
    const float* b1    = (const float*)d_in[4];
    const float* W2    = (const float*)d_in[5];
    const float* b2    = (const float*)d_in[6];
    const float* pos   = (const float*)d_in[7];
    float* ws  = (float*)d_ws;
    float* out = (float*)d_out;

    hipLaunchKernelGGL(preK,   dim3(16),    dim3(256), 0, stream, pos, ws);
    hipLaunchKernelGGL(pre2b,  dim3(255),   dim3(128), 0, stream, W_enc, b_enc, pos, ws);
    hipLaunchKernelGGL(mainker, dim3(PAIRS), dim3(256), 0, stream, x, W1, b1, W2, b2, ws, out);
}

// Round 19
// 117.139 us; speedup vs baseline: 1.0205x; 1.0205x over previous
//
#include <hip/hip_runtime.h>

#define B_ 32
#define D_ 64
#define N_ 254
#define L_ 16
#define H_ 128
#define P_ 96
#define PAIRS (B_*D_)    // 2048
#define XPAIR (N_*L_)    // 4064 floats per (b,d) pair
#define OUT0  (B_*P_*D_) // 196608 floats (output 0)

// ws layout (floats):
#define WS_M    128    // [256]  M = W_enc W_enc^T  ([l1*16+l2])
#define WS_VK   384    // [16]   W_enc @ K,  K = 254*b_enc + colsum(pos)
#define WS_BW   400    // [16]   W_enc @ b_enc
#define WS_BK   416    // [1]    b_enc . K
#define WS_G    432    // [254*16] pos @ W_enc^T  ([n*16+l])
#define WS_PK   4496   // [254]  pos @ K
#define WS_KP   4752   // [16*128] partial column sums of pos

typedef float f32x4 __attribute__((ext_vector_type(4)));

// ---- stage 1: partial column sums of pos (254 x 128), coalesced ----
__global__ __launch_bounds__(256) void preK(const float* __restrict__ pos,
                                            float* __restrict__ ws) {
    __shared__ float red[256];
    int t = threadIdx.x;
    int h = t & 127, j = t >> 7;          // j in {0,1}
    int n0 = blockIdx.x * 16;             // 16 blocks x 16 rows (last: 14)
    float acc = 0.f;
    #pragma unroll
    for (int r = 0; r < 8; r++) {
        int n = n0 + j + 2 * r;
        if (n < N_) acc += pos[n * H_ + h];
    }
    red[t] = acc;
    __syncthreads();
    if (t < 128) ws[WS_KP + blockIdx.x * 128 + t] = red[t] + red[t + 128];
}

// ---- stage 2: G,pK (blocks 0..253) + M,vK,bW,bK (block 254) ----
__global__ __launch_bounds__(128) void pre2b(const float* __restrict__ W_enc,
                                             const float* __restrict__ b_enc,
                                             const float* __restrict__ pos,
                                             float* __restrict__ ws) {
    __shared__ float Ks[128], bL[128], pLDS[128], red[128], red2[128];
    __shared__ float WL[2048];
    int t = threadIdx.x;                  // 128 threads
    int n = blockIdx.x;                   // 0..254

    // rebuild K locally (L2-hot partials): K[h] = 254*b_enc[h] + sum_g part
    {
        float b = b_enc[t];
        float s = 254.f * b;
        #pragma unroll
        for (int g = 0; g < 16; g++) s += ws[WS_KP + g * 128 + t];
        Ks[t] = s;
        bL[t] = b;
    }

    if (n < N_) {
        pLDS[t] = pos[n * H_ + t];
        __syncthreads();
        // G partials: t -> (l = t>>3, c = t&7), 16-wide h-chunk each
        {
            int l = t >> 3, c = t & 7;
            const float* w = W_enc + l * H_ + c * 16;
            const float* p = pLDS + c * 16;
            float s = 0.f;
            #pragma unroll
            for (int i = 0; i < 16; i++) s += p[i] * w[i];
            red[t] = s;
            red2[t] = pLDS[t] * Ks[t];
        }
        __syncthreads();
        if (t < 16) {                     // G final
            float s = 0.f;
            #pragma unroll
            for (int c = 0; c < 8; c++) s += red[t * 8 + c];
            ws[WS_G + n * 16 + t] = s;
        }
        if (t >= 64) {                    // pK final (wave 1)
            int lane = t - 64;
            float s = red2[lane] + red2[lane + 64];
            for (int off = 32; off; off >>= 1) s += __shfl_down(s, off);
            if (lane == 0) ws[WS_PK + n] = s;
        }
    } else {
        // block 254: stage W_enc (16x128) into LDS, then tiny dots
        for (int i = t; i < 512; i += 128) {
            float4 v = ((const float4*)W_enc)[i];
            float* p = &WL[i * 4];
            p[0] = v.x; p[1] = v.y; p[2] = v.z; p[3] = v.w;
        }
        __syncthreads();
        #pragma unroll
        for (int e0 = 0; e0 < 2; e0++) {  // M: 256 entries / 128 threads
            int e = e0 * 128 + t;
            int l1 = e >> 4, l2 = e & 15;
            float s = 0.f;
            for (int h = 0; h < H_; h++) s += WL[l1 * H_ + h] * WL[l2 * H_ + h];
            ws[WS_M + e] = s;
        }
        if (t < 16) {
            float s1 = 0.f, s2 = 0.f;
            for (int h = 0; h < H_; h++) {
                float w = WL[t * H_ + h];
                s1 += w * Ks[h];
                s2 += w * bL[h];
            }
            ws[WS_VK + t] = s1;
            ws[WS_BW + t] = s2;
        }
        if (t == 16) {
            float s = 0.f;
            for (int h = 0; h < H_; h++) s += bL[h] * Ks[h];
            ws[WS_BK] = s;
        }
    }
}

// ---- main: x in registers (thread t owns quad t&3 of rows t>>2 + {0,64,128,192}).
//      Copy-stores DEFERRED to the epilogue: __syncthreads drains vmcnt(0), so
//      stores before barrier 1 would serialize every block's early critical path.
//      LDS reduction trees kept (R18 showed shfl butterflies regress at full
//      occupancy: serial 16-DS-op chains vs latency-hidden LDS round-trips). ----
__global__ __launch_bounds__(256) void mainker(const float* __restrict__ x,
                                               const float* __restrict__ W1,
                                               const float* __restrict__ b1,
                                               const float* __restrict__ W2,
                                               const float* __restrict__ b2,
                                               const float* __restrict__ ws,
                                               float* __restrict__ out) {
    __shared__ f32x4 red4[256];          // 4 KB reduction scratch
    __shared__ float scoreS[256];        // padded to 256
    __shared__ float xsS[16], vS[16], pooledS[16], hS[128];
    __shared__ float s0S, denomS;

    int t  = threadIdx.x;
    int bd = blockIdx.x;                 // b*64 + d
    int q  = t & 3, r0 = t >> 2;         // quad, base row

    const f32x4* xv = (const f32x4*)(x + (size_t)bd * XPAIR);
    f32x4*       cv = (f32x4*)(out + OUT0) + (size_t)bd * (XPAIR / 4);

    f32x4 v0 = xv[t];
    f32x4 v1 = xv[t + 256];
    f32x4 v2 = xv[t + 512];
    f32x4 v3 = {0.f, 0.f, 0.f, 0.f};
    bool has3 = (t < 248);               // rows 254/255 don't exist
    if (has3) v3 = xv[t + 768];

    // ---- xs partials: one float4 per thread ----
    red4[t] = v0 + v1 + v2 + v3;
    __syncthreads();
    if (t < 64) red4[t] = red4[t] + red4[t + 64] + red4[t + 128] + red4[t + 192];
    __syncthreads();

    // ---- wave0: xs final + v = vK + M xs + s0 = bK + xs.bW ----
    if (t < 16) {
        float xsv = 0.f;
        #pragma unroll
        for (int m = 0; m < 16; m++) xsv += red4[m * 4 + (t >> 2)][t & 3];
        xsS[t] = xsv;
        float s = ws[WS_VK + t];
        #pragma unroll
        for (int l2 = 0; l2 < 16; l2++) s += __shfl(xsv, l2) * ws[WS_M + l2 * 16 + t];
        vS[t] = s;
        float s0p = xsv * ws[WS_BW + t];
        #pragma unroll
        for (int off = 8; off; off >>= 1) s0p += __shfl_down(s0p, off);
        if (t == 0) s0S = ws[WS_BK] + s0p;
    }
    __syncthreads();

    // ---- score[n] by 4-lane groups from registers; G reads coalesced float4 ----
    {
        float vq0 = vS[4*q], vq1 = vS[4*q+1], vq2 = vS[4*q+2], vq3 = vS[4*q+3];
        float xq0 = xsS[4*q], xq1 = xsS[4*q+1], xq2 = xsS[4*q+2], xq3 = xsS[4*q+3];
        #pragma unroll
        for (int k = 0; k < 4; k++) {
            if (k < 3 || has3) {
                int rk = r0 + 64 * k;
                f32x4 xk = (k == 0) ? v0 : (k == 1) ? v1 : (k == 2) ? v2 : v3;
                f32x4 g  = *(const f32x4*)(ws + WS_G + rk * 16 + 4 * q);
                float s = xk[0]*vq0 + xk[1]*vq1 + xk[2]*vq2 + xk[3]*vq3
                        + xq0*g[0] + xq1*g[1] + xq2*g[2] + xq3*g[3];
                s += __shfl_xor(s, 1);
                s += __shfl_xor(s, 2);
                if (q == 0) scoreS[rk] = s + s0S + ws[WS_PK + rk];
            }
        }
    }
    __syncthreads();

    // ---- denom (wave 0) overlapped with pooled partials (all threads) ----
    if (t < 64) {
        float s = 0.f;
        for (int n = t; n < N_; n += 64) s += fabsf(scoreS[n]);
        for (int off = 32; off; off >>= 1) s += __shfl_down(s, off);
        if (t == 0) denomS = s;
    }
    {
        f32x4 p4 = v0 * scoreS[r0] + v1 * scoreS[r0 + 64] + v2 * scoreS[r0 + 128];
        if (has3) p4 += v3 * scoreS[r0 + 192];
        red4[t] = p4;
    }
    __syncthreads();
    if (t < 64) red4[t] = red4[t] + red4[t + 64] + red4[t + 128] + red4[t + 192];
    __syncthreads();
    if (t < 16) {
        float invd = 1.0f / denomS;
        float s = 0.f;
        #pragma unroll
        for (int m = 0; m < 16; m++) s += red4[m * 4 + (t >> 2)][t & 3];
        pooledS[t] = s * invd;
    }
    __syncthreads();

    // ---- h = leaky_relu(pooled @ W1 + b1, 0.2) ----
    if (t < 128) {
        float s = b1[t];
        #pragma unroll
        for (int l = 0; l < 16; l++) s += pooledS[l] * W1[l * H_ + t];
        hS[t] = s > 0.f ? s : 0.2f * s;
    }
    __syncthreads();

    // ---- deferred copy-stores: after the last barrier, no barrier waits on them ----
    cv[t]       = v0;
    cv[t + 256] = v1;
    cv[t + 512] = v2;
    if (has3) cv[t + 768] = v3;

    // ---- out0[b, p, d] = h @ W2 + b2 : coalesced scalar W2 (lane-consecutive) ----
    if (t < 96) {
        float s = b2[t];
        for (int j = 0; j < 128; j++) s += hS[j] * W2[j * P_ + t];
        int b = bd >> 6, d = bd & 63;
        out[b * (P_ * D_) + t * D_ + d] = s;
    }
}

extern "C" void kernel_launch(void* const* d_in, const int* in_sizes, int n_in,
                              void* d_out, int out_size, void* d_ws, size_t ws_size,
                              hipStream_t stream) {
    const float* x     = (const float*)d_in[0];
    const float* W_enc = (const float*)d_in[1];
    const float* b_enc = (const float*)d_in[2];
    const float* W1    = (const float*)d_in[3];
    const float* b1    = (const float*)d_in[4];
    const float* W2    = (const float*)d_in[5];
    const float* b2    = (const float*)d_in[6];
    const float* pos   = (const float*)d_in[7];
    float* ws  = (float*)d_ws;
    float* out = (float*)d_out;

    hipLaunchKernelGGL(preK,   dim3(16),    dim3(256), 0, stream, pos, ws);
    hipLaunchKernelGGL(pre2b,  dim3(255),   dim3(128), 0, stream, W_enc, b_enc, pos, ws);
    hipLaunchKernelGGL(mainker, dim3(PAIRS), dim3(256), 0, stream, x, W1, b1, W2, b2, ws, out);
}